// Round 18
// baseline (224.667 us; speedup 1.0000x reference)
//
#include <hip/hip_runtime.h>

#define EMBED 64
#define BSHIFT 9
#define BROWS 512      // rows per coarse bucket
#define NGROUPS 256    // passA/passB write-front groups (private fronts)
#define PTHREADS 1024  // threads for the big preprocessing kernels
#define MAXNB 512      // max buckets supported by LDS arrays (nb=293 here)
#define SCAN_THREADS 256
#define SCAN_ITEMS 16
#define SCAN_TILE (SCAN_THREADS * SCAN_ITEMS)  // 4096
// tpack: (row & 511) << 20 | col   (col < 2^20; n_nodes = 150K fits)
// eoff: BYTE offset col<<7 (row stride 128 B); pad row = n_nodes<<7
// CSR is DEGREE-SORTED within each bucket: rs_p[pos] is position-indexed
// (contiguous edge lists for a wave's 8 equal-degree rows); rowstart[row] +
// deg[row] give the row-indexed view for gather_sel.

typedef unsigned short ushort_t;
typedef __attribute__((ext_vector_type(2))) float f32x2;

__device__ __forceinline__ ushort_t f2bf(float f) {  // RTNE
    unsigned u = __float_as_uint(f);
    return (ushort_t)((u + 0x7FFFu + ((u >> 16) & 1u)) >> 16);
}
__device__ __forceinline__ float bf2f(ushort_t b) {
    return __uint_as_float(((unsigned)b) << 16);
}

// Generic per-tile exclusive scan: in -> out (tile-local) + tile sums.
__global__ void scan_tiles(const int* __restrict__ in, int* __restrict__ out,
                           int* __restrict__ tile_sums, int n) {
    __shared__ int sh[SCAN_THREADS];
    int t = threadIdx.x;
    int base = blockIdx.x * SCAN_TILE + t * SCAN_ITEMS;
    int vals[SCAN_ITEMS];
    int sum = 0;
#pragma unroll
    for (int k = 0; k < SCAN_ITEMS; ++k) {
        int idx = base + k;
        vals[k] = (idx < n) ? in[idx] : 0;
        sum += vals[k];
    }
    sh[t] = sum;
    __syncthreads();
    for (int off = 1; off < SCAN_THREADS; off <<= 1) {
        int v = (t >= off) ? sh[t - off] : 0;
        __syncthreads();
        sh[t] += v;
        __syncthreads();
    }
    int excl = sh[t] - sum;
    if (t == SCAN_THREADS - 1) tile_sums[blockIdx.x] = sh[t];
    int run = excl;
#pragma unroll
    for (int k = 0; k < SCAN_ITEMS; ++k) {
        int idx = base + k;
        if (idx < n) out[idx] = run;
        run += vals[k];
    }
}

// Folded scan_bases+add_bases: each thread re-sums the (<=19) tile sums.
__global__ void add_bases_f(int* __restrict__ arr, const int* __restrict__ tile_sums,
                            int n, int ntiles) {
    int i = blockIdx.x * blockDim.x + threadIdx.x;
    if (i >= n) {
        if (i == n) {
            int s = 0;
            for (int j = 0; j < ntiles; ++j) s += tile_sums[j];
            arr[n] = s;
        }
        return;
    }
    int myt = i / SCAN_TILE;
    int base = 0;
    for (int j = 0; j < myt; ++j) base += tile_sums[j];
    arr[i] += base;
}

// passA: per-group LDS histogram over coarse buckets -> cnt[bucket][group].
__global__ __launch_bounds__(PTHREADS) void passA_hist(const int* __restrict__ row,
                                                       int* __restrict__ cnt,
                                                       int nnz, int nb, int epb) {
    __shared__ int hist[MAXNB];
    int g = blockIdx.x, t = threadIdx.x;
    for (int b = t; b < nb; b += PTHREADS) hist[b] = 0;
    __syncthreads();
    int i0 = g * epb, i1 = min(i0 + epb, nnz);
    for (int i = i0 + t; i < i1; i += PTHREADS) atomicAdd(&hist[row[i] >> BSHIFT], 1);
    __syncthreads();
    for (int b = t; b < nb; b += PTHREADS) cnt[b * NGROUPS + g] = hist[b];
}

// passB: deterministic scatter into group-private dense fronts (LDS cursors,
// no global atomics). 4 B/edge: (rlocal<<20)|col.
__global__ __launch_bounds__(PTHREADS) void passB_scatter(const int* __restrict__ row,
                                                          const int* __restrict__ col,
                                                          const int* __restrict__ cbase,
                                                          int* __restrict__ tpack,
                                                          int nnz, int nb, int epb) {
    __shared__ int lcur[MAXNB];
    int g = blockIdx.x, t = threadIdx.x;
    for (int b = t; b < nb; b += PTHREADS) lcur[b] = cbase[b * NGROUPS + g];
    __syncthreads();
    int i0 = g * epb, i1 = min(i0 + epb, nnz);
    for (int i = i0 + t; i < i1; i += PTHREADS) {
        int r = row[i];
        int slot = atomicAdd(&lcur[r >> BSHIFT], 1);
        tpack[slot] = ((r & (BROWS - 1)) << 20) | col[i];
    }
}

// Fully fused per-bucket build with DEGREE-SORTED CSR: deg + dinv + within-
// bucket degree-sorted perm + perm-ordered edge bases (rs_p position-indexed,
// rowstart row-indexed) + eoff placement at sorted bases + pre-scaled bf16 x0.
__global__ __launch_bounds__(PTHREADS) void build_bucket(const int* __restrict__ cbase,
                                                         const int* __restrict__ tpack,
                                                         const float* __restrict__ ue,
                                                         const float* __restrict__ ie,
                                                         int* __restrict__ deg,
                                                         float* __restrict__ dinv,
                                                         int* __restrict__ rowstart,
                                                         int* __restrict__ rs_p,
                                                         int* __restrict__ eoff,
                                                         int* __restrict__ perm,
                                                         ushort_t* __restrict__ xa,
                                                         ushort_t* __restrict__ xb,
                                                         ushort_t* __restrict__ xc,
                                                         int n_nodes, int n_users, int nnz) {
    __shared__ int hist[BROWS];   // deg per rlocal
    __shared__ int sscan[BROWS];  // scan scratch
    __shared__ int lcur[BROWS];   // temp sorted-deg copy, then row-local cursors
    __shared__ int ccur[BROWS];   // class counts -> class bases -> pos-indexed rowstart
    __shared__ int sslot[BROWS];  // rlocal -> sorted position
    __shared__ float sdinv[BROWS];
    int b = blockIdx.x, t = threadIdx.x;
    int r0 = b * BROWS;
    int r1 = min(r0 + BROWS, n_nodes);
    int nrows = r1 - r0;
    for (int r = t; r < BROWS; r += PTHREADS) { hist[r] = 0; ccur[r] = 0; }
    __syncthreads();
    int es = cbase[b * NGROUPS];
    int ee = cbase[(b + 1) * NGROUPS];  // cbase[n2] == nnz
    for (int e = es + t; e < ee; e += PTHREADS) atomicAdd(&hist[((unsigned)tpack[e]) >> 20], 1);
    __syncthreads();
    if (t < nrows) {
        int d = hist[t];
        deg[r0 + t] = d;
        float di = 1.0f / sqrtf((float)max(d, 1));
        dinv[r0 + t] = di;
        sdinv[t] = di;
        atomicAdd(&ccur[min(d, BROWS - 1)], 1);  // degree-class counts
    }
    __syncthreads();
    // class-count scan -> exclusive class bases
    if (t < BROWS) sscan[t] = ccur[t];
    __syncthreads();
    for (int off = 1; off < BROWS; off <<= 1) {
        int v = 0;
        if (t < BROWS && t >= off) v = sscan[t - off];
        __syncthreads();
        if (t < BROWS) sscan[t] += v;
        __syncthreads();
    }
    if (t < BROWS) ccur[t] = sscan[t] - ccur[t];
    __syncthreads();
    // slot assignment + perm (within-bucket degree order)
    if (t < nrows) {
        int cls = min(hist[t], BROWS - 1);
        int s = atomicAdd(&ccur[cls], 1);
        sslot[t] = s;
        perm[r0 + s] = r0 + t;
    }
    // sorted-degree array -> sscan (positions >= nrows stay 0)
    if (t < BROWS) sscan[t] = 0;
    __syncthreads();
    if (t < nrows) sscan[sslot[t]] = hist[t];
    __syncthreads();
    if (t < BROWS) lcur[t] = sscan[t];  // keep sorted deg for exclusive calc
    __syncthreads();
    for (int off = 1; off < BROWS; off <<= 1) {  // scan sorted degs
        int v = 0;
        if (t < BROWS && t >= off) v = sscan[t - off];
        __syncthreads();
        if (t < BROWS) sscan[t] += v;
        __syncthreads();
    }
    if (t < BROWS) ccur[t] = es + sscan[t] - lcur[t];  // pos-indexed rowstart
    __syncthreads();
    if (t < nrows) {
        int rstart = ccur[sslot[t]];
        lcur[t] = rstart;          // row-local placement cursor
        rowstart[r0 + t] = rstart; // row-indexed (gather_sel)
        rs_p[r0 + t] = ccur[t];    // position-indexed (spmm); t is a position here
    }
    if (b == 0 && t == 0) rs_p[n_nodes] = nnz;
    __syncthreads();
    // placement: bucket-grouped tpack -> degree-sorted-CSR eoff (byte offsets)
    for (int e = es + t; e < ee; e += PTHREADS) {
        int pk = tpack[e];
        int slot = atomicAdd(&lcur[((unsigned)pk) >> 20], 1);
        eoff[slot] = (pk & 0xFFFFF) << 7;
    }
    // pre-scaled x0 for this bucket's rows
    int nq = nrows * 16;  // ushort4 quads in this bucket
    for (int idx = t; idx < nq; idx += PTHREADS) {
        int rl = idx >> 4, q = idx & 15;
        int grow = r0 + rl;
        const float* src = (grow < n_users) ? (ue + (size_t)grow * EMBED)
                                            : (ie + (size_t)(grow - n_users) * EMBED);
        float4 v = ((const float4*)src)[q];
        float d = sdinv[rl];
        ushort4 o;
        o.x = f2bf(d * v.x); o.y = f2bf(d * v.y); o.z = f2bf(d * v.z); o.w = f2bf(d * v.w);
        ((ushort4*)(xa + (size_t)grow * EMBED))[q] = o;
    }
    if (b == 0 && t < 48) {  // zero the pad row (index n_nodes) of all 3 buffers
        ushort4 z = {0, 0, 0, 0};
        ushort_t* tgt = (t < 16) ? xa : ((t < 32) ? xb : xc);
        ((ushort4*)(tgt + (size_t)n_nodes * EMBED))[t & 15] = z;
    }
}

// SPMM v9 — sorted CSR + COLUMN-MAJOR wave->chunk assignment. r17's sorted
// CSR fixed locality (FETCH at floor) but blocks covering 4 consecutive
// chunks inherited the bucket's degree saw-tooth -> wildly variable block
// durations -> scheduling tail (occ 48%). Column-major (wave w of block b
// takes chunk w*gridDim + b) spaces a block's 4 chunks gridDim(~4688) apart;
// 4688 mod 64(chunks/bucket) = 16 -> phases {0,16,32,48} = one chunk per
// degree quartile -> uniform block durations, no tail. Per-wave balance and
// contiguous edge lists preserved.
__global__ __launch_bounds__(256, 8) void spmm_bf16(const int* __restrict__ rs_p,
                                                    const int* __restrict__ eoff,
                                                    const int* __restrict__ perm,
                                                    const float* __restrict__ dinv,
                                                    const ushort_t* __restrict__ x,
                                                    ushort_t* __restrict__ y, int n_nodes) {
    int wave = (threadIdx.x >> 6) * gridDim.x + blockIdx.x;  // column-major
    int lane = threadIdx.x & 63;
    int g = lane >> 3;   // row subgroup 0..7
    int l8 = lane & 7;   // dim-oct within row (and step-offset for id prefetch)
    int idx = wave * 8 + g;
    bool valid = idx < n_nodes;
    int row = valid ? perm[idx] : 0;
    int start = valid ? rs_p[idx] : 0;
    int end = valid ? rs_p[idx + 1] : 0;
    int maxdeg = end - start;
#pragma unroll
    for (int m = 1; m < 64; m <<= 1) maxdeg = max(maxdeg, __shfl_xor(maxdeg, m));
    int pad = n_nodes << 7;
    const char* xb = (const char*)x + (l8 << 4);  // per-lane 16B slice base
    f32x2 a0 = 0.f, a1 = 0.f, a2 = 0.f, a3 = 0.f;
#define GATH(K)                                                                           \
    {                                                                                     \
        int cc = __shfl(c_lane, (g << 3) + K);                                            \
        uint4 q = *(const uint4*)(xb + cc);                                               \
        a0 += (f32x2){__uint_as_float(q.x << 16), __uint_as_float(q.x & 0xFFFF0000u)};    \
        a1 += (f32x2){__uint_as_float(q.y << 16), __uint_as_float(q.y & 0xFFFF0000u)};    \
        a2 += (f32x2){__uint_as_float(q.z << 16), __uint_as_float(q.z & 0xFFFF0000u)};    \
        a3 += (f32x2){__uint_as_float(q.w << 16), __uint_as_float(q.w & 0xFFFF0000u)};    \
    }
    for (int k0 = 0; k0 < maxdeg; k0 += 8) {
        int il = start + k0 + l8;                  // lane prefetches id for step k0+l8 of ITS row
        int c_lane = (il < end) ? eoff[il] : pad;  // past-end steps -> zero row
        int nk = maxdeg - k0;
        if (nk > 8) nk = 8;  // wave-uniform
        switch (nk) {
            case 8: GATH(7); [[fallthrough]];
            case 7: GATH(6); [[fallthrough]];
            case 6: GATH(5); [[fallthrough]];
            case 5: GATH(4); [[fallthrough]];
            case 4: GATH(3); [[fallthrough]];
            case 3: GATH(2); [[fallthrough]];
            case 2: GATH(1); [[fallthrough]];
            case 1: GATH(0);
        }
    }
#undef GATH
    if (valid) {
        float dr = dinv[row];
        float s = dr * dr;
        uint4 o;
        o.x = (unsigned)f2bf(s * a0.x) | ((unsigned)f2bf(s * a0.y) << 16);
        o.y = (unsigned)f2bf(s * a1.x) | ((unsigned)f2bf(s * a1.y) << 16);
        o.z = (unsigned)f2bf(s * a2.x) | ((unsigned)f2bf(s * a2.y) << 16);
        o.w = (unsigned)f2bf(s * a3.x) | ((unsigned)f2bf(s * a3.y) << 16);
        *(uint4*)(y + (size_t)row * EMBED + l8 * 8) = o;
    }
}

// Fused layer-3 + final gather, restricted to the 3*batch sampled rows.
// Row-indexed CSR view: start = rowstart[node], end = start + deg[node].
//   out = 0.25*(e0_exact + sd*(x~1 + x~2) + dinv*sum_{c in N(r)} x~2[c])
__global__ __launch_bounds__(256, 8) void gather_sel(const int* __restrict__ rowstart,
                                                     const int* __restrict__ deg,
                                                     const int* __restrict__ eoff,
                                                     const float* __restrict__ dinv,
                                                     const float* __restrict__ ue,
                                                     const float* __restrict__ ie,
                                                     const ushort_t* __restrict__ x1,
                                                     const ushort_t* __restrict__ x2,
                                                     const int* __restrict__ users,
                                                     const int* __restrict__ pos,
                                                     const int* __restrict__ neg,
                                                     float* __restrict__ out,
                                                     int batch, int n_users, int n_nodes) {
    int w = blockIdx.x * (blockDim.x >> 6) + (threadIdx.x >> 6);
    int total = 3 * batch;
    if (w >= total) return;
    int lane = threadIdx.x & 63;
    int g = lane >> 3;   // edge subgroup 0..7
    int l8 = lane & 7;   // dim-oct
    int which = w / batch;
    int b = w - which * batch;
    int node;
    const float* e0p;
    if (which == 0) {
        int u = users[b];
        node = u;
        e0p = ue + (size_t)u * EMBED;
    } else {
        int it = (which == 1) ? pos[b] : neg[b];
        node = n_users + it;
        e0p = ie + (size_t)it * EMBED;
    }
    int start = rowstart[node];
    int end = start + deg[node];
    int pad = n_nodes << 7;
    const char* xb = (const char*)x2 + (l8 << 4);
    f32x2 a0 = 0.f, a1 = 0.f, a2 = 0.f, a3 = 0.f;
#define GATH(K)                                                                           \
    {                                                                                     \
        int cc = __shfl(c_lane, (K << 3) + g);                                            \
        uint4 q = *(const uint4*)(xb + cc);                                               \
        a0 += (f32x2){__uint_as_float(q.x << 16), __uint_as_float(q.x & 0xFFFF0000u)};    \
        a1 += (f32x2){__uint_as_float(q.y << 16), __uint_as_float(q.y & 0xFFFF0000u)};    \
        a2 += (f32x2){__uint_as_float(q.z << 16), __uint_as_float(q.z & 0xFFFF0000u)};    \
        a3 += (f32x2){__uint_as_float(q.w << 16), __uint_as_float(q.w & 0xFFFF0000u)};    \
    }
    for (int base = start; base < end; base += 64) {
        int m = end - base;
        if (m > 64) m = 64;
        int il = base + lane;
        int c_lane = (il < end) ? eoff[il] : pad;
        int nk = (m + 7) >> 3;
        switch (nk) {
            case 8: GATH(7); [[fallthrough]];
            case 7: GATH(6); [[fallthrough]];
            case 6: GATH(5); [[fallthrough]];
            case 5: GATH(4); [[fallthrough]];
            case 4: GATH(3); [[fallthrough]];
            case 3: GATH(2); [[fallthrough]];
            case 2: GATH(1); [[fallthrough]];
            case 1: GATH(0);
        }
    }
#undef GATH
    float r0 = a0.x, r1 = a0.y, r2 = a1.x, r3 = a1.y;
    float r4 = a2.x, r5 = a2.y, r6 = a3.x, r7 = a3.y;
#pragma unroll
    for (int msk = 8; msk <= 32; msk <<= 1) {
        r0 += __shfl_xor(r0, msk);
        r1 += __shfl_xor(r1, msk);
        r2 += __shfl_xor(r2, msk);
        r3 += __shfl_xor(r3, msk);
        r4 += __shfl_xor(r4, msk);
        r5 += __shfl_xor(r5, msk);
        r6 += __shfl_xor(r6, msk);
        r7 += __shfl_xor(r7, msk);
    }
    if (g == 0) {
        float dr = dinv[node];
        float sd = 1.0f / dr;  // sqrt(max(deg,1))
        size_t xoff = (size_t)node * EMBED + l8 * 8;
        uint4 q1 = *(const uint4*)(x1 + xoff);
        uint4 q2 = *(const uint4*)(x2 + xoff);
        float4 e0a = *(const float4*)(e0p + l8 * 8);
        float4 e0b = *(const float4*)(e0p + l8 * 8 + 4);
        float l12_0 = bf2f((ushort_t)(q1.x & 0xFFFF)) + bf2f((ushort_t)(q2.x & 0xFFFF));
        float l12_1 = bf2f((ushort_t)(q1.x >> 16)) + bf2f((ushort_t)(q2.x >> 16));
        float l12_2 = bf2f((ushort_t)(q1.y & 0xFFFF)) + bf2f((ushort_t)(q2.y & 0xFFFF));
        float l12_3 = bf2f((ushort_t)(q1.y >> 16)) + bf2f((ushort_t)(q2.y >> 16));
        float l12_4 = bf2f((ushort_t)(q1.z & 0xFFFF)) + bf2f((ushort_t)(q2.z & 0xFFFF));
        float l12_5 = bf2f((ushort_t)(q1.z >> 16)) + bf2f((ushort_t)(q2.z >> 16));
        float l12_6 = bf2f((ushort_t)(q1.w & 0xFFFF)) + bf2f((ushort_t)(q2.w & 0xFFFF));
        float l12_7 = bf2f((ushort_t)(q1.w >> 16)) + bf2f((ushort_t)(q2.w >> 16));
        float* op = out + (size_t)w * EMBED + l8 * 8;
        float4 o0, o1;
        o0.x = 0.25f * (e0a.x + sd * l12_0 + dr * r0);
        o0.y = 0.25f * (e0a.y + sd * l12_1 + dr * r1);
        o0.z = 0.25f * (e0a.z + sd * l12_2 + dr * r2);
        o0.w = 0.25f * (e0a.w + sd * l12_3 + dr * r3);
        o1.x = 0.25f * (e0b.x + sd * l12_4 + dr * r4);
        o1.y = 0.25f * (e0b.y + sd * l12_5 + dr * r5);
        o1.z = 0.25f * (e0b.z + sd * l12_6 + dr * r6);
        o1.w = 0.25f * (e0b.w + sd * l12_7 + dr * r7);
        *(float4*)op = o0;
        *(float4*)(op + 4) = o1;
    }
}

extern "C" void kernel_launch(void* const* d_in, const int* in_sizes, int n_in,
                              void* d_out, int out_size, void* d_ws, size_t ws_size,
                              hipStream_t stream) {
    const float* user_emb = (const float*)d_in[0];
    const float* item_emb = (const float*)d_in[1];
    const int* row = (const int*)d_in[2];
    const int* col = (const int*)d_in[3];
    const int* users = (const int*)d_in[5];
    const int* pos = (const int*)d_in[6];
    const int* neg = (const int*)d_in[7];
    float* out = (float*)d_out;

    int n_users = in_sizes[0] / EMBED;
    int n_items = in_sizes[1] / EMBED;
    int n_nodes = n_users + n_items;
    int nnz = in_sizes[2];
    int batch = in_sizes[5];
    int nb = (n_nodes + BROWS - 1) / BROWS;   // 293
    int n2 = nb * NGROUPS;                    // 75008
    int epb = (nnz + NGROUPS - 1) / NGROUPS;  // 12500

    char* p = (char*)d_ws;
    auto alloc = [&](size_t bytes) -> void* {
        void* r = (void*)p;
        p += (bytes + 255) & ~(size_t)255;
        return r;
    };
    int ntiles2 = (n2 + SCAN_TILE - 1) / SCAN_TILE;
    int* deg = (int*)alloc(sizeof(int) * (size_t)n_nodes);
    int* rowstart = (int*)alloc(sizeof(int) * (size_t)n_nodes);
    int* rs_p = (int*)alloc(sizeof(int) * ((size_t)n_nodes + 16));
    float* dinv = (float*)alloc(sizeof(float) * (size_t)n_nodes);
    int* perm = (int*)alloc(sizeof(int) * ((size_t)n_nodes + 8));
    int* cnt = (int*)alloc(sizeof(int) * (size_t)n2);
    int* cbase = (int*)alloc(sizeof(int) * (size_t)(n2 + 1));
    int* tile_sums = (int*)alloc(sizeof(int) * (size_t)ntiles2);
    int* eoff = (int*)alloc(sizeof(int) * ((size_t)nnz + 64));  // +64: tail reads
    ushort_t* bufA = (ushort_t*)alloc(sizeof(ushort_t) * (size_t)(n_nodes + 1) * EMBED);
    ushort_t* bufB = (ushort_t*)alloc(sizeof(ushort_t) * (size_t)(n_nodes + 1) * EMBED);
    ushort_t* bufC = (ushort_t*)alloc(sizeof(ushort_t) * (size_t)(n_nodes + 1) * EMBED);
    if ((size_t)(p - (char*)d_ws) > ws_size) return;  // workspace too small: bail visibly
    // tpack (12.8MB) aliases bufB (19.2MB): consumed by build_bucket before the
    // first spmm writes bufB. build_bucket writes x0 into bufA only; bufB's pad
    // row (offset 19.2MB) is beyond tpack's 12.8MB.
    int* tpack = (int*)bufB;

    passA_hist<<<NGROUPS, PTHREADS, 0, stream>>>(row, cnt, nnz, nb, epb);
    scan_tiles<<<ntiles2, SCAN_THREADS, 0, stream>>>(cnt, cbase, tile_sums, n2);
    add_bases_f<<<(n2 + 256) / 256, 256, 0, stream>>>(cbase, tile_sums, n2, ntiles2);
    passB_scatter<<<NGROUPS, PTHREADS, 0, stream>>>(row, col, cbase, tpack, nnz, nb, epb);
    build_bucket<<<nb, PTHREADS, 0, stream>>>(cbase, tpack, user_emb, item_emb, deg, dinv,
                                              rowstart, rs_p, eoff, perm, bufA, bufB, bufC,
                                              n_nodes, n_users, nnz);

    int waves = (n_nodes + 7) / 8;          // 8 rows per wave
    int spmm_blocks = (waves + 3) / 4;      // 4 waves per block
    spmm_bf16<<<spmm_blocks, 256, 0, stream>>>(rs_p, eoff, perm, dinv, bufA, bufB, n_nodes);
    spmm_bf16<<<spmm_blocks, 256, 0, stream>>>(rs_p, eoff, perm, dinv, bufB, bufC, n_nodes);

    int selw = 3 * batch;
    gather_sel<<<(selw + 3) / 4, 256, 0, stream>>>(rowstart, deg, eoff, dinv, user_emb,
                                                   item_emb, bufB, bufC, users, pos, neg,
                                                   out, batch, n_users, n_nodes);
}

// Round 19
// 205.080 us; speedup vs baseline: 1.0955x; 1.0955x over previous
//
#include <hip/hip_runtime.h>

#define EMBED 64
#define BSHIFT 9
#define BROWS 512      // rows per coarse bucket
#define NGROUPS 256    // passA/passB write-front groups (private fronts)
#define PTHREADS 1024  // threads for the big preprocessing kernels
#define MAXNB 512      // max buckets supported by LDS arrays (nb=293 here)
#define SCAN_THREADS 256
#define SCAN_ITEMS 16
#define SCAN_TILE (SCAN_THREADS * SCAN_ITEMS)  // 4096
// tpack: (row & 511) << 20 | col   (col < 2^20; n_nodes = 150K fits)
// eoff: BYTE offset col<<7 (row stride 128 B); pad row = n_nodes<<7
// NOTE (r15-r18): every attempt to degree-balance spmm waves (global sort,
// within-bucket perm, sorted CSR, col-major chunk assignment) cost MORE in
// L2/L3 locality than balance recovered. Natural address order = FETCH at the
// 153.6MB compulsory floor (8 XCD x 19.2MB). Keep natural order.

typedef unsigned short ushort_t;
typedef __attribute__((ext_vector_type(2))) float f32x2;

__device__ __forceinline__ ushort_t f2bf(float f) {  // RTNE
    unsigned u = __float_as_uint(f);
    return (ushort_t)((u + 0x7FFFu + ((u >> 16) & 1u)) >> 16);
}
__device__ __forceinline__ float bf2f(ushort_t b) {
    return __uint_as_float(((unsigned)b) << 16);
}

// Generic per-tile exclusive scan: in -> out (tile-local) + tile sums.
__global__ void scan_tiles(const int* __restrict__ in, int* __restrict__ out,
                           int* __restrict__ tile_sums, int n) {
    __shared__ int sh[SCAN_THREADS];
    int t = threadIdx.x;
    int base = blockIdx.x * SCAN_TILE + t * SCAN_ITEMS;
    int vals[SCAN_ITEMS];
    int sum = 0;
#pragma unroll
    for (int k = 0; k < SCAN_ITEMS; ++k) {
        int idx = base + k;
        vals[k] = (idx < n) ? in[idx] : 0;
        sum += vals[k];
    }
    sh[t] = sum;
    __syncthreads();
    for (int off = 1; off < SCAN_THREADS; off <<= 1) {
        int v = (t >= off) ? sh[t - off] : 0;
        __syncthreads();
        sh[t] += v;
        __syncthreads();
    }
    int excl = sh[t] - sum;
    if (t == SCAN_THREADS - 1) tile_sums[blockIdx.x] = sh[t];
    int run = excl;
#pragma unroll
    for (int k = 0; k < SCAN_ITEMS; ++k) {
        int idx = base + k;
        if (idx < n) out[idx] = run;
        run += vals[k];
    }
}

// Folded scan_bases+add_bases: each thread re-sums the (<=19) tile sums.
__global__ void add_bases_f(int* __restrict__ arr, const int* __restrict__ tile_sums,
                            int n, int ntiles) {
    int i = blockIdx.x * blockDim.x + threadIdx.x;
    if (i >= n) {
        if (i == n) {
            int s = 0;
            for (int j = 0; j < ntiles; ++j) s += tile_sums[j];
            arr[n] = s;
        }
        return;
    }
    int myt = i / SCAN_TILE;
    int base = 0;
    for (int j = 0; j < myt; ++j) base += tile_sums[j];
    arr[i] += base;
}

// passA: per-group LDS histogram over coarse buckets -> cnt[bucket][group].
__global__ __launch_bounds__(PTHREADS) void passA_hist(const int* __restrict__ row,
                                                       int* __restrict__ cnt,
                                                       int nnz, int nb, int epb) {
    __shared__ int hist[MAXNB];
    int g = blockIdx.x, t = threadIdx.x;
    for (int b = t; b < nb; b += PTHREADS) hist[b] = 0;
    __syncthreads();
    int i0 = g * epb, i1 = min(i0 + epb, nnz);
    for (int i = i0 + t; i < i1; i += PTHREADS) atomicAdd(&hist[row[i] >> BSHIFT], 1);
    __syncthreads();
    for (int b = t; b < nb; b += PTHREADS) cnt[b * NGROUPS + g] = hist[b];
}

// passB: deterministic scatter into group-private dense fronts (LDS cursors,
// no global atomics). 4 B/edge: (rlocal<<20)|col.
__global__ __launch_bounds__(PTHREADS) void passB_scatter(const int* __restrict__ row,
                                                          const int* __restrict__ col,
                                                          const int* __restrict__ cbase,
                                                          int* __restrict__ tpack,
                                                          int nnz, int nb, int epb) {
    __shared__ int lcur[MAXNB];
    int g = blockIdx.x, t = threadIdx.x;
    for (int b = t; b < nb; b += PTHREADS) lcur[b] = cbase[b * NGROUPS + g];
    __syncthreads();
    int i0 = g * epb, i1 = min(i0 + epb, nnz);
    for (int i = i0 + t; i < i1; i += PTHREADS) {
        int r = row[i];
        int slot = atomicAdd(&lcur[r >> BSHIFT], 1);
        tpack[slot] = ((r & (BROWS - 1)) << 20) | col[i];
    }
}

// Fully fused per-bucket build: deg + dinv + offs (in-LDS scan) + eoff
// placement (pass2) + pre-scaled bf16 x0 rows + pad-row zeroing.
__global__ __launch_bounds__(PTHREADS) void build_bucket(const int* __restrict__ cbase,
                                                         const int* __restrict__ tpack,
                                                         const float* __restrict__ ue,
                                                         const float* __restrict__ ie,
                                                         int* __restrict__ deg,
                                                         float* __restrict__ dinv,
                                                         int* __restrict__ offs,
                                                         int* __restrict__ eoff,
                                                         ushort_t* __restrict__ xa,
                                                         ushort_t* __restrict__ xb,
                                                         ushort_t* __restrict__ xc,
                                                         int n_nodes, int n_users, int nnz) {
    __shared__ int hist[BROWS];
    __shared__ int sscan[BROWS];
    __shared__ int lcur[BROWS];
    __shared__ float sdinv[BROWS];
    int b = blockIdx.x, t = threadIdx.x;
    int r0 = b * BROWS;
    int r1 = min(r0 + BROWS, n_nodes);
    for (int r = t; r < BROWS; r += PTHREADS) hist[r] = 0;
    __syncthreads();
    int es = cbase[b * NGROUPS];
    int ee = cbase[(b + 1) * NGROUPS];  // cbase[n2] == nnz
    for (int e = es + t; e < ee; e += PTHREADS) atomicAdd(&hist[((unsigned)tpack[e]) >> 20], 1);
    __syncthreads();
    if (t < BROWS) sscan[t] = hist[t];
    __syncthreads();
    for (int off = 1; off < BROWS; off <<= 1) {  // Hillis-Steele inclusive scan
        int v = 0;
        if (t < BROWS && t >= off) v = sscan[t - off];
        __syncthreads();
        if (t < BROWS) sscan[t] += v;
        __syncthreads();
    }
    if (t < BROWS) {
        int d = hist[t];
        int excl = es + sscan[t] - d;
        lcur[t] = excl;
        if (t < r1 - r0) {
            deg[r0 + t] = d;
            float di = 1.0f / sqrtf((float)max(d, 1));
            dinv[r0 + t] = di;
            sdinv[t] = di;
            offs[r0 + t] = excl;
        }
    }
    if (b == 0 && t == 0) offs[n_nodes] = nnz;
    __syncthreads();
    // pass2 placement: bucket-grouped tpack -> row-grouped eoff (byte offsets)
    for (int e = es + t; e < ee; e += PTHREADS) {
        int pk = tpack[e];
        int slot = atomicAdd(&lcur[((unsigned)pk) >> 20], 1);
        eoff[slot] = (pk & 0xFFFFF) << 7;
    }
    // pre-scaled x0 for this bucket's rows
    int nq = (r1 - r0) * 16;  // ushort4 quads in this bucket
    for (int idx = t; idx < nq; idx += PTHREADS) {
        int rl = idx >> 4, q = idx & 15;
        int grow = r0 + rl;
        const float* src = (grow < n_users) ? (ue + (size_t)grow * EMBED)
                                            : (ie + (size_t)(grow - n_users) * EMBED);
        float4 v = ((const float4*)src)[q];
        float d = sdinv[rl];
        ushort4 o;
        o.x = f2bf(d * v.x); o.y = f2bf(d * v.y); o.z = f2bf(d * v.z); o.w = f2bf(d * v.w);
        ((ushort4*)(xa + (size_t)grow * EMBED))[q] = o;
    }
    if (b == 0 && t < 48) {  // zero the pad row (index n_nodes) of all 3 buffers
        ushort4 z = {0, 0, 0, 0};
        ushort_t* tgt = (t < 16) ? xa : ((t < 32) ? xb : xc);
        ((ushort4*)(tgt + (size_t)n_nodes * EMBED))[t & 15] = z;
    }
}

// SPMM v5 (r14 best) — transposed decomposition, NATURAL row order: 8 groups
// = 8 consecutive rows per wave, 8 lanes x uint4 = one full 128B row per
// edge. Each group's row accumulates entirely in-lane -> epilogue is scale +
// one 16B store, ZERO cross-lane reduction. Wave runs max(deg of its 8 rows)
// steps; idle groups gather the L1-hot zero pad row (~1.2-1.4x imbalance pad
// — every balancing scheme tried (r15-r18) lost more to locality than it
// gained). TLP discipline: low VGPR, 8 waves/SIMD (r10 lesson).
__global__ __launch_bounds__(256, 8) void spmm_bf16(const int* __restrict__ offs,
                                                    const int* __restrict__ eoff,
                                                    const float* __restrict__ dinv,
                                                    const ushort_t* __restrict__ x,
                                                    ushort_t* __restrict__ y, int n_nodes) {
    int wave = blockIdx.x * (blockDim.x >> 6) + (threadIdx.x >> 6);
    int lane = threadIdx.x & 63;
    int g = lane >> 3;   // row subgroup 0..7
    int l8 = lane & 7;   // dim-oct within row (and step-offset for id prefetch)
    int row = wave * 8 + g;
    bool valid = row < n_nodes;
    int start = valid ? offs[row] : 0;
    int end = valid ? offs[row + 1] : 0;
    int maxdeg = end - start;
#pragma unroll
    for (int m = 1; m < 64; m <<= 1) maxdeg = max(maxdeg, __shfl_xor(maxdeg, m));
    int pad = n_nodes << 7;
    const char* xb = (const char*)x + (l8 << 4);  // per-lane 16B slice base
    f32x2 a0 = 0.f, a1 = 0.f, a2 = 0.f, a3 = 0.f;
#define GATH(K)                                                                           \
    {                                                                                     \
        int cc = __shfl(c_lane, (g << 3) + K);                                            \
        uint4 q = *(const uint4*)(xb + cc);                                               \
        a0 += (f32x2){__uint_as_float(q.x << 16), __uint_as_float(q.x & 0xFFFF0000u)};    \
        a1 += (f32x2){__uint_as_float(q.y << 16), __uint_as_float(q.y & 0xFFFF0000u)};    \
        a2 += (f32x2){__uint_as_float(q.z << 16), __uint_as_float(q.z & 0xFFFF0000u)};    \
        a3 += (f32x2){__uint_as_float(q.w << 16), __uint_as_float(q.w & 0xFFFF0000u)};    \
    }
    for (int k0 = 0; k0 < maxdeg; k0 += 8) {
        int il = start + k0 + l8;                  // lane prefetches id for step k0+l8 of ITS row
        int c_lane = (il < end) ? eoff[il] : pad;  // past-end steps -> zero row
        int nk = maxdeg - k0;
        if (nk > 8) nk = 8;  // wave-uniform
        switch (nk) {
            case 8: GATH(7); [[fallthrough]];
            case 7: GATH(6); [[fallthrough]];
            case 6: GATH(5); [[fallthrough]];
            case 5: GATH(4); [[fallthrough]];
            case 4: GATH(3); [[fallthrough]];
            case 3: GATH(2); [[fallthrough]];
            case 2: GATH(1); [[fallthrough]];
            case 1: GATH(0);
        }
    }
#undef GATH
    if (valid) {
        float dr = dinv[row];
        float s = dr * dr;
        uint4 o;
        o.x = (unsigned)f2bf(s * a0.x) | ((unsigned)f2bf(s * a0.y) << 16);
        o.y = (unsigned)f2bf(s * a1.x) | ((unsigned)f2bf(s * a1.y) << 16);
        o.z = (unsigned)f2bf(s * a2.x) | ((unsigned)f2bf(s * a2.y) << 16);
        o.w = (unsigned)f2bf(s * a3.x) | ((unsigned)f2bf(s * a3.y) << 16);
        *(uint4*)(y + (size_t)row * EMBED + l8 * 8) = o;
    }
}

// Fused layer-3 + final gather, restricted to the 3*batch sampled rows (12x
// less gather work than a full L3 spmm). One wave per output row:
//   out = 0.25*(e0_exact + sd*(x~1 + x~2) + dinv*sum_{c in N(r)} x~2[c])
__global__ __launch_bounds__(256, 8) void gather_sel(const int* __restrict__ offs,
                                                     const int* __restrict__ eoff,
                                                     const float* __restrict__ dinv,
                                                     const float* __restrict__ ue,
                                                     const float* __restrict__ ie,
                                                     const ushort_t* __restrict__ x1,
                                                     const ushort_t* __restrict__ x2,
                                                     const int* __restrict__ users,
                                                     const int* __restrict__ pos,
                                                     const int* __restrict__ neg,
                                                     float* __restrict__ out,
                                                     int batch, int n_users, int n_nodes) {
    int w = blockIdx.x * (blockDim.x >> 6) + (threadIdx.x >> 6);
    int total = 3 * batch;
    if (w >= total) return;
    int lane = threadIdx.x & 63;
    int g = lane >> 3;   // edge subgroup 0..7
    int l8 = lane & 7;   // dim-oct
    int which = w / batch;
    int b = w - which * batch;
    int node;
    const float* e0p;
    if (which == 0) {
        int u = users[b];
        node = u;
        e0p = ue + (size_t)u * EMBED;
    } else {
        int it = (which == 1) ? pos[b] : neg[b];
        node = n_users + it;
        e0p = ie + (size_t)it * EMBED;
    }
    int start = offs[node];
    int end = offs[node + 1];
    int pad = n_nodes << 7;
    const char* xb = (const char*)x2 + (l8 << 4);
    f32x2 a0 = 0.f, a1 = 0.f, a2 = 0.f, a3 = 0.f;
#define GATH(K)                                                                           \
    {                                                                                     \
        int cc = __shfl(c_lane, (K << 3) + g);                                            \
        uint4 q = *(const uint4*)(xb + cc);                                               \
        a0 += (f32x2){__uint_as_float(q.x << 16), __uint_as_float(q.x & 0xFFFF0000u)};    \
        a1 += (f32x2){__uint_as_float(q.y << 16), __uint_as_float(q.y & 0xFFFF0000u)};    \
        a2 += (f32x2){__uint_as_float(q.z << 16), __uint_as_float(q.z & 0xFFFF0000u)};    \
        a3 += (f32x2){__uint_as_float(q.w << 16), __uint_as_float(q.w & 0xFFFF0000u)};    \
    }
    for (int base = start; base < end; base += 64) {
        int m = end - base;
        if (m > 64) m = 64;
        int il = base + lane;
        int c_lane = (il < end) ? eoff[il] : pad;
        int nk = (m + 7) >> 3;
        switch (nk) {
            case 8: GATH(7); [[fallthrough]];
            case 7: GATH(6); [[fallthrough]];
            case 6: GATH(5); [[fallthrough]];
            case 5: GATH(4); [[fallthrough]];
            case 4: GATH(3); [[fallthrough]];
            case 3: GATH(2); [[fallthrough]];
            case 2: GATH(1); [[fallthrough]];
            case 1: GATH(0);
        }
    }
#undef GATH
    float r0 = a0.x, r1 = a0.y, r2 = a1.x, r3 = a1.y;
    float r4 = a2.x, r5 = a2.y, r6 = a3.x, r7 = a3.y;
#pragma unroll
    for (int msk = 8; msk <= 32; msk <<= 1) {
        r0 += __shfl_xor(r0, msk);
        r1 += __shfl_xor(r1, msk);
        r2 += __shfl_xor(r2, msk);
        r3 += __shfl_xor(r3, msk);
        r4 += __shfl_xor(r4, msk);
        r5 += __shfl_xor(r5, msk);
        r6 += __shfl_xor(r6, msk);
        r7 += __shfl_xor(r7, msk);
    }
    if (g == 0) {
        float dr = dinv[node];
        float sd = 1.0f / dr;  // sqrt(max(deg,1))
        size_t xoff = (size_t)node * EMBED + l8 * 8;
        uint4 q1 = *(const uint4*)(x1 + xoff);
        uint4 q2 = *(const uint4*)(x2 + xoff);
        float4 e0a = *(const float4*)(e0p + l8 * 8);
        float4 e0b = *(const float4*)(e0p + l8 * 8 + 4);
        float l12_0 = bf2f((ushort_t)(q1.x & 0xFFFF)) + bf2f((ushort_t)(q2.x & 0xFFFF));
        float l12_1 = bf2f((ushort_t)(q1.x >> 16)) + bf2f((ushort_t)(q2.x >> 16));
        float l12_2 = bf2f((ushort_t)(q1.y & 0xFFFF)) + bf2f((ushort_t)(q2.y & 0xFFFF));
        float l12_3 = bf2f((ushort_t)(q1.y >> 16)) + bf2f((ushort_t)(q2.y >> 16));
        float l12_4 = bf2f((ushort_t)(q1.z & 0xFFFF)) + bf2f((ushort_t)(q2.z & 0xFFFF));
        float l12_5 = bf2f((ushort_t)(q1.z >> 16)) + bf2f((ushort_t)(q2.z >> 16));
        float l12_6 = bf2f((ushort_t)(q1.w & 0xFFFF)) + bf2f((ushort_t)(q2.w & 0xFFFF));
        float l12_7 = bf2f((ushort_t)(q1.w >> 16)) + bf2f((ushort_t)(q2.w >> 16));
        float* op = out + (size_t)w * EMBED + l8 * 8;
        float4 o0, o1;
        o0.x = 0.25f * (e0a.x + sd * l12_0 + dr * r0);
        o0.y = 0.25f * (e0a.y + sd * l12_1 + dr * r1);
        o0.z = 0.25f * (e0a.z + sd * l12_2 + dr * r2);
        o0.w = 0.25f * (e0a.w + sd * l12_3 + dr * r3);
        o1.x = 0.25f * (e0b.x + sd * l12_4 + dr * r4);
        o1.y = 0.25f * (e0b.y + sd * l12_5 + dr * r5);
        o1.z = 0.25f * (e0b.z + sd * l12_6 + dr * r6);
        o1.w = 0.25f * (e0b.w + sd * l12_7 + dr * r7);
        *(float4*)op = o0;
        *(float4*)(op + 4) = o1;
    }
}

extern "C" void kernel_launch(void* const* d_in, const int* in_sizes, int n_in,
                              void* d_out, int out_size, void* d_ws, size_t ws_size,
                              hipStream_t stream) {
    const float* user_emb = (const float*)d_in[0];
    const float* item_emb = (const float*)d_in[1];
    const int* row = (const int*)d_in[2];
    const int* col = (const int*)d_in[3];
    const int* users = (const int*)d_in[5];
    const int* pos = (const int*)d_in[6];
    const int* neg = (const int*)d_in[7];
    float* out = (float*)d_out;

    int n_users = in_sizes[0] / EMBED;
    int n_items = in_sizes[1] / EMBED;
    int n_nodes = n_users + n_items;
    int nnz = in_sizes[2];
    int batch = in_sizes[5];
    int nb = (n_nodes + BROWS - 1) / BROWS;   // 293
    int n2 = nb * NGROUPS;                    // 75008
    int epb = (nnz + NGROUPS - 1) / NGROUPS;  // 12500

    char* p = (char*)d_ws;
    auto alloc = [&](size_t bytes) -> void* {
        void* r = (void*)p;
        p += (bytes + 255) & ~(size_t)255;
        return r;
    };
    int ntiles2 = (n2 + SCAN_TILE - 1) / SCAN_TILE;
    int* deg = (int*)alloc(sizeof(int) * (size_t)n_nodes);
    int* offs = (int*)alloc(sizeof(int) * (size_t)(n_nodes + 1));
    float* dinv = (float*)alloc(sizeof(float) * (size_t)n_nodes);
    int* cnt = (int*)alloc(sizeof(int) * (size_t)n2);
    int* cbase = (int*)alloc(sizeof(int) * (size_t)(n2 + 1));
    int* tile_sums = (int*)alloc(sizeof(int) * (size_t)ntiles2);
    int* eoff = (int*)alloc(sizeof(int) * ((size_t)nnz + 64));  // +64: tail reads
    ushort_t* bufA = (ushort_t*)alloc(sizeof(ushort_t) * (size_t)(n_nodes + 1) * EMBED);
    ushort_t* bufB = (ushort_t*)alloc(sizeof(ushort_t) * (size_t)(n_nodes + 1) * EMBED);
    ushort_t* bufC = (ushort_t*)alloc(sizeof(ushort_t) * (size_t)(n_nodes + 1) * EMBED);
    if ((size_t)(p - (char*)d_ws) > ws_size) return;  // workspace too small: bail visibly
    // tpack (12.8MB) aliases bufB (19.2MB): consumed by build_bucket before the
    // first spmm writes bufB. build_bucket writes x0 into bufA only; bufB's pad
    // row (offset 19.2MB) is beyond tpack's 12.8MB.
    int* tpack = (int*)bufB;

    passA_hist<<<NGROUPS, PTHREADS, 0, stream>>>(row, cnt, nnz, nb, epb);
    scan_tiles<<<ntiles2, SCAN_THREADS, 0, stream>>>(cnt, cbase, tile_sums, n2);
    add_bases_f<<<(n2 + 256) / 256, 256, 0, stream>>>(cbase, tile_sums, n2, ntiles2);
    passB_scatter<<<NGROUPS, PTHREADS, 0, stream>>>(row, col, cbase, tpack, nnz, nb, epb);
    build_bucket<<<nb, PTHREADS, 0, stream>>>(cbase, tpack, user_emb, item_emb, deg, dinv,
                                              offs, eoff, bufA, bufB, bufC, n_nodes,
                                              n_users, nnz);

    int waves = (n_nodes + 7) / 8;          // 8 rows per wave
    int spmm_blocks = (waves + 3) / 4;      // 4 waves per block
    spmm_bf16<<<spmm_blocks, 256, 0, stream>>>(offs, eoff, dinv, bufA, bufB, n_nodes);  // L1
    spmm_bf16<<<spmm_blocks, 256, 0, stream>>>(offs, eoff, dinv, bufB, bufC, n_nodes);  // L2

    int selw = 3 * batch;
    gather_sel<<<(selw + 3) / 4, 256, 0, stream>>>(offs, eoff, dinv, user_emb, item_emb,
                                                   bufB, bufC, users, pos, neg, out,
                                                   batch, n_users, n_nodes);
}